// Round 2
// baseline (364.878 us; speedup 1.0000x reference)
//
#include <hip/hip_runtime.h>
#include <hip/hip_fp16.h>

#define NE 400000
#define NN 25000
#define MAXDEG 56       // Poisson(16): P(deg>=56) ~ 1e-15
#define LDS_STRIDE 65

typedef __attribute__((ext_vector_type(8))) _Float16 half8;
typedef __attribute__((ext_vector_type(4))) _Float16 half4;
typedef __attribute__((ext_vector_type(4))) float f32x4;

// ---------- ws layout (5.74 MB — mix16 eliminated by fusion) ----------
#define WS_SLOTS_OFF 0ull            // int, NN*56 = 5,600,000 B
#define WS_CNT_OFF   5600000ull      // int, NN    =   100,000 B
#define WS_WBUF_OFF  5700000ull      // _Float16, 18,432 f16 = 36,864 B
#define WS_NEED      5736864ull

// wbuf frag bases (f16 units): L0: 4 frags, L1: 8, L2: 8, L3: 16 (frag = 512 f16)
#define WB_L0 0
#define WB_L1 2048
#define WB_L2 6144
#define WB_L3 10240

__device__ __forceinline__ float fast_silu(float x) {
    float e = __expf(-x);
    return x * __builtin_amdgcn_rcpf(1.0f + e);
}

// ---------------- weights -> fragment-linear f16 (+ cnt zeroing) ----------------
// frag elem at lane l, j: W[kt*32 + (l>>4)*8 + j][nt*16 + (l&15)] * scale
// (serves as A-frag of W^T: m = nt*16+(l&15), k = kt*32+(l>>4)*8+j)
__global__ __launch_bounds__(64) void prep_weights(
    const float* __restrict__ W0, const float* __restrict__ W1,
    const float* __restrict__ W2, const float* __restrict__ W3,
    _Float16* __restrict__ wbuf, int* __restrict__ cnt)
{
    const int f    = blockIdx.x;      // 0..35
    const int lane = threadIdx.x;

    // zero cnt (must complete before csr_build launch; stream-ordered)
    for (int i = f * 64 + lane; i < NN; i += 36 * 64) cnt[i] = 0;

    const int n    = lane & 15;
    const int quad = lane >> 4;

    const float* W; int K, N, kt, nt, fl, base; float scale;
    if (f < 4)       { W = W0; K = 8;  N = 64;  fl = f;      kt = 0;       nt = fl;     scale = 0.35355339059327373f; base = WB_L0; }
    else if (f < 12) { W = W1; K = 64; N = 64;  fl = f - 4;  kt = fl >> 2; nt = fl & 3; scale = 0.125f;   base = WB_L1; }
    else if (f < 20) { W = W2; K = 64; N = 64;  fl = f - 12; kt = fl >> 2; nt = fl & 3; scale = 0.125f;   base = WB_L2; }
    else             { W = W3; K = 64; N = 128; fl = f - 20; kt = fl >> 3; nt = fl & 7; scale = 0.03125f; base = WB_L3; }
    // 0.03125 = 1/sqrt(64) fan-in * 1/sqrt(16) avg-neighbors folded into W3

    _Float16 v[8];
    #pragma unroll
    for (int j = 0; j < 8; ++j) {
        const int k = kt * 32 + quad * 8 + j;
        const float val = (k < K) ? W[k * N + nt * 16 + n] * scale : 0.0f;
        v[j] = (_Float16)val;
    }
    *(half8*)(wbuf + base + fl * 512 + lane * 8) = *(const half8*)v;
}

// ---------------- CSR build (padded slots per receiver) ----------------
__global__ __launch_bounds__(256) void csr_build(
    const int* __restrict__ receivers, int* __restrict__ cnt, int* __restrict__ slots)
{
    const int e = blockIdx.x * 256 + threadIdx.x;
    if (e < NE) {
        const int r = receivers[e];
        const int s = atomicAdd(&cnt[r], 1);
        if (s < MAXDEG) slots[r * MAXDEG + s] = e;
    }
}

// ---------------- fused MLP + combine + aggregate: one wave per node ----------------
// Block = 256 thr = 4 waves = 4 nodes. Weights staged to LDS once per block.
// Per wave, per 16-edge tile of its node: gather edge_feats -> 4-layer MFMA MLP
// (same fragment layouts as the proven mlp_build) -> consume L3 accumulator
// IN REGISTERS: for L3 weight-tile nt, lane (q,c) holds irreps 0..3 of channel
// ch=4*nt+q for edge-slot c (since m = nt*16+4q+r = 4*ch+r). Combine with
// node_feats[snd][ch] / edge_attrs[eid] immediately, accumulate per-lane
// acc[nt][j]; final sum over the 16 edge-slots = 4-step shfl_xor butterfly.
// mix16 (204 MB of HBM round-trip) is eliminated entirely.
#define HS 72   // H stride (f16): 144 B
__global__ __launch_bounds__(256) void fused_mp_kernel(
    const float*    __restrict__ node_feats,   // (NN, 32, 4)
    const float*    __restrict__ edge_attrs,   // (NE, 4)
    const float*    __restrict__ edge_feats,   // (NE, 8)
    const int*      __restrict__ senders,      // (NE,)
    const _Float16* __restrict__ wbuf,         // 18432 f16
    const int*      __restrict__ cnt,
    const int*      __restrict__ slots,
    float*          __restrict__ out)          // (NN, 32, 8)
{
    __shared__ _Float16 WL[18432];             // 36,864 B: all weight frags
    __shared__ _Float16 H[4 * 16 * HS];        // per-wave 16x64 activation tile

    const int tid = threadIdx.x;
    // ---- stage weights to LDS (once per block) ----
    {
        const half8* src = (const half8*)wbuf;
        half8*       dst = (half8*)WL;
        #pragma unroll
        for (int i = 0; i < 9; ++i) dst[i * 256 + tid] = src[i * 256 + tid];
    }
    __syncthreads();   // only barrier; after this, waves run independently

    const int wave = tid >> 6;
    const int lane = tid & 63;
    const int c    = lane & 15;                // edge slot within tile
    const int q    = lane >> 4;
    const int n    = blockIdx.x * 4 + wave;    // NN = 6250*4 exact
    const float inv_sqrt3 = 0.5773502691896258f;

    int d = cnt[n];
    if (d > MAXDEG) d = MAXDEG;
    const int* sl = slots + n * MAXDEG;

    // ---- prefetch CSR row: lane l holds edge l (clamped) ----
    const int li    = (lane < MAXDEG) ? lane : (MAXDEG - 1);
    int eid_l       = sl[li];
    eid_l           = (lane < d) ? eid_l : 0;  // mask garbage before any use
    const int snd_l = senders[eid_l];

    float acc[8][8];
    #pragma unroll
    for (int nt = 0; nt < 8; ++nt)
        #pragma unroll
        for (int j = 0; j < 8; ++j) acc[nt][j] = 0.0f;

    _Float16* HW = &H[wave * 16 * HS];
    const half8* wb = (const half8*)WL;
    const f32x4 zero4 = {0.f, 0.f, 0.f, 0.f};

    const int ntiles = (d + 15) >> 4;          // 0..4
    for (int t = 0; t < ntiles; ++t) {
        const int  slot = t * 16 + c;          // this lane's edge slot
        const int  eid  = __shfl(eid_l, slot, 64);  // lanes >= d hold clamped 0
        const int  snd  = __shfl(snd_l, slot, 64);
        const bool act  = (slot < d);

        // ---- B-frag for L0 (k=0..7 live in quad 0; rest zero) ----
        half8 b0 = {0, 0, 0, 0, 0, 0, 0, 0};
        if (q == 0) {
            const float4* p = (const float4*)(edge_feats + (size_t)eid * 8);
            const float4 x = p[0], y = p[1];
            b0[0] = (_Float16)x.x; b0[1] = (_Float16)x.y; b0[2] = (_Float16)x.z; b0[3] = (_Float16)x.w;
            b0[4] = (_Float16)y.x; b0[5] = (_Float16)y.y; b0[6] = (_Float16)y.z; b0[7] = (_Float16)y.w;
        }

        // ---- L0: 8(->32) -> 64 ----
        #pragma unroll
        for (int nt = 0; nt < 4; ++nt) {
            const half8 w = wb[(WB_L0 / 512 + nt) * 64 + lane];
            f32x4 a = __builtin_amdgcn_mfma_f32_16x16x32_f16(w, b0, zero4, 0, 0, 0);
            half4 h;
            #pragma unroll
            for (int r = 0; r < 4; ++r) h[r] = (_Float16)fast_silu(a[r]);
            *(half4*)&HW[c * HS + nt * 16 + q * 4] = h;
        }

        // ---- L1, L2: 64 -> 64 (DS in-order per wave: no barriers) ----
        #pragma unroll
        for (int layer = 0; layer < 2; ++layer) {
            const int wbase = (layer == 0 ? WB_L1 : WB_L2) / 512;
            const half8 blo = *(const half8*)&HW[c * HS + 0  + q * 8];
            const half8 bhi = *(const half8*)&HW[c * HS + 32 + q * 8];
            f32x4 a[4];
            #pragma unroll
            for (int nt = 0; nt < 4; ++nt) {
                const half8 wlo = wb[(wbase + 0 + nt) * 64 + lane];
                const half8 whi = wb[(wbase + 4 + nt) * 64 + lane];
                a[nt] = __builtin_amdgcn_mfma_f32_16x16x32_f16(wlo, blo, zero4, 0, 0, 0);
                a[nt] = __builtin_amdgcn_mfma_f32_16x16x32_f16(whi, bhi, a[nt], 0, 0, 0);
            }
            #pragma unroll
            for (int nt = 0; nt < 4; ++nt) {
                half4 h;
                #pragma unroll
                for (int r = 0; r < 4; ++r) h[r] = (_Float16)fast_silu(a[nt][r]);
                *(half4*)&HW[c * HS + nt * 16 + q * 4] = h;
            }
        }

        // ---- L3 + in-register combine ----
        {
            const half8 blo = *(const half8*)&HW[c * HS + 0  + q * 8];
            const half8 bhi = *(const half8*)&HW[c * HS + 32 + q * 8];

            const float4 a4 = ((const float4*)edge_attrs)[eid];   // L2-hot, 4 dup lanes
            const float as = a4.x, av0 = a4.y, av1 = a4.z, av2 = a4.w;
            const float z  = act ? 1.0f : 0.0f;

            // prefetch node_feats channels ch = 4*nt+q for this lane's edge
            const float4* nfp = (const float4*)(node_feats + (size_t)snd * 128);
            float4 nf[8];
            #pragma unroll
            for (int nt = 0; nt < 8; ++nt) nf[nt] = nfp[4 * nt + q];

            #pragma unroll
            for (int nt = 0; nt < 8; ++nt) {
                const half8 wlo = wb[(WB_L3 / 512 + 0 + nt) * 64 + lane];
                const half8 whi = wb[(WB_L3 / 512 + 8 + nt) * 64 + lane];
                f32x4 a = __builtin_amdgcn_mfma_f32_16x16x32_f16(wlo, blo, zero4, 0, 0, 0);
                a = __builtin_amdgcn_mfma_f32_16x16x32_f16(whi, bhi, a, 0, 0, 0);
                const float m0 = z * a[0], m1 = z * a[1];
                const float m2 = z * a[2], m3 = z * a[3];
                const float sc = nf[nt].x, v0 = nf[nt].y, v1 = nf[nt].z, v2 = nf[nt].w;
                acc[nt][0] = fmaf(sc * as, m0, acc[nt][0]);
                const float dv = v0 * av0 + v1 * av1 + v2 * av2;
                acc[nt][1] = fmaf(dv * inv_sqrt3, m1, acc[nt][1]);
                acc[nt][2] = fmaf(sc * av0, m2, acc[nt][2]);
                acc[nt][3] = fmaf(sc * av1, m2, acc[nt][3]);
                acc[nt][4] = fmaf(sc * av2, m2, acc[nt][4]);
                acc[nt][5] = fmaf(v0 * as, m3, acc[nt][5]);
                acc[nt][6] = fmaf(v1 * as, m3, acc[nt][6]);
                acc[nt][7] = fmaf(v2 * as, m3, acc[nt][7]);
            }
        }
    }

    // ---- reduce over the 16 edge slots (lanes within each q-group) ----
    #pragma unroll
    for (int nt = 0; nt < 8; ++nt)
        #pragma unroll
        for (int j = 0; j < 8; ++j) {
            float v = acc[nt][j];
            v += __shfl_xor(v, 1, 64);
            v += __shfl_xor(v, 2, 64);
            v += __shfl_xor(v, 4, 64);
            v += __shfl_xor(v, 8, 64);
            acc[nt][j] = v;
        }

    // ---- store: lane (q, c==0) writes channels {4*nt+q} x 8 outputs ----
    // out element (ch*8+j) = 32*nt + 8*q + j  -> two float4 per nt
    if (c == 0) {
        float* op = out + (size_t)n * 256 + q * 8;
        #pragma unroll
        for (int nt = 0; nt < 8; ++nt) {
            float4 lo, hi;
            lo.x = acc[nt][0]; lo.y = acc[nt][1]; lo.z = acc[nt][2]; lo.w = acc[nt][3];
            hi.x = acc[nt][4]; hi.y = acc[nt][5]; hi.z = acc[nt][6]; hi.w = acc[nt][7];
            ((float4*)(op + nt * 32))[0] = lo;
            ((float4*)(op + nt * 32 + 4))[0] = hi;
        }
    }   // deg-0 nodes: acc==0 -> zeros written
}

// ---------------- fallback: monolithic atomic kernel (correct but slow) ----------------
__global__ __launch_bounds__(128) void edge_mp_kernel(
    const float* __restrict__ node_feats, const float* __restrict__ edge_attrs,
    const float* __restrict__ edge_feats, const int* __restrict__ senders,
    const int* __restrict__ receivers, const float* __restrict__ W0,
    const float* __restrict__ W1, const float* __restrict__ W2,
    const float* __restrict__ W3, float* __restrict__ out)
{
    __shared__ float hbuf[128 * LDS_STRIDE];
    const int tid = threadIdx.x;
    const int e   = blockIdx.x * 128 + tid;
    if (e >= NE) return;
    float* hl = &hbuf[tid * LDS_STRIDE];

    float4 ef0 = ((const float4*)edge_feats)[e * 2 + 0];
    float4 ef1 = ((const float4*)edge_feats)[e * 2 + 1];
    float ef[8] = {ef0.x, ef0.y, ef0.z, ef0.w, ef1.x, ef1.y, ef1.z, ef1.w};
    float acc[64];
    #pragma unroll
    for (int i = 0; i < 64; ++i) acc[i] = 0.0f;
    #pragma unroll
    for (int j = 0; j < 8; ++j) {
        const float xj = ef[j];
        const float* wrow = W0 + j * 64;
        #pragma unroll
        for (int i = 0; i < 64; ++i) acc[i] = fmaf(xj, wrow[i], acc[i]);
    }
    {
        const float s0 = 0.35355339059327373f;
        #pragma unroll
        for (int i = 0; i < 64; ++i) hl[i] = fast_silu(acc[i] * s0);
    }
    #pragma unroll
    for (int i = 0; i < 64; ++i) acc[i] = 0.0f;
    #pragma unroll 4
    for (int j = 0; j < 64; ++j) {
        const float xj = hl[j];
        const float* wrow = W1 + j * 64;
        #pragma unroll
        for (int i = 0; i < 64; ++i) acc[i] = fmaf(xj, wrow[i], acc[i]);
    }
    #pragma unroll
    for (int i = 0; i < 64; ++i) hl[i] = fast_silu(acc[i] * 0.125f);
    #pragma unroll
    for (int i = 0; i < 64; ++i) acc[i] = 0.0f;
    #pragma unroll 4
    for (int j = 0; j < 64; ++j) {
        const float xj = hl[j];
        const float* wrow = W2 + j * 64;
        #pragma unroll
        for (int i = 0; i < 64; ++i) acc[i] = fmaf(xj, wrow[i], acc[i]);
    }
    float h2[64];
    #pragma unroll
    for (int i = 0; i < 64; ++i) h2[i] = fast_silu(acc[i] * 0.125f);

    const int snd = senders[e];
    const int rcv = receivers[e];
    const float4 a4 = ((const float4*)edge_attrs)[e];
    const float a_s = a4.x, av0 = a4.y, av1 = a4.z, av2 = a4.w;
    const float4* nf4 = (const float4*)(node_feats + (size_t)snd * 128);
    float* outp = out + (size_t)rcv * 256;
    const float mixscale = 0.03125f;
    const float inv_sqrt3 = 0.5773502691896258f;

    #pragma unroll 2
    for (int c = 0; c < 32; ++c) {
        float m0 = 0.0f, m1 = 0.0f, m2 = 0.0f, m3 = 0.0f;
        const float* wc = W3 + c * 4;
        #pragma unroll
        for (int j = 0; j < 64; ++j) {
            const float hj = h2[j];
            m0 = fmaf(hj, wc[j * 128 + 0], m0);
            m1 = fmaf(hj, wc[j * 128 + 1], m1);
            m2 = fmaf(hj, wc[j * 128 + 2], m2);
            m3 = fmaf(hj, wc[j * 128 + 3], m3);
        }
        m0 *= mixscale; m1 *= mixscale; m2 *= mixscale; m3 *= mixscale;
        const float4 x4 = nf4[c];
        const float s = x4.x, v0 = x4.y, v1 = x4.z, v2 = x4.w;
        float* op = outp + c * 8;
        atomicAdd(op + 0, s * a_s * m0);
        const float dotva = v0 * av0 + v1 * av1 + v2 * av2;
        atomicAdd(op + 1, dotva * inv_sqrt3 * m1);
        atomicAdd(op + 2, s * av0 * m2);
        atomicAdd(op + 3, s * av1 * m2);
        atomicAdd(op + 4, s * av2 * m2);
        atomicAdd(op + 5, v0 * a_s * m3);
        atomicAdd(op + 6, v1 * a_s * m3);
        atomicAdd(op + 7, v2 * a_s * m3);
    }
}

extern "C" void kernel_launch(void* const* d_in, const int* in_sizes, int n_in,
                              void* d_out, int out_size, void* d_ws, size_t ws_size,
                              hipStream_t stream) {
    const float* node_feats = (const float*)d_in[0];
    const float* edge_attrs = (const float*)d_in[1];
    const float* edge_feats = (const float*)d_in[2];
    const int*   senders    = (const int*)d_in[3];
    const int*   receivers  = (const int*)d_in[4];
    const float* W0 = (const float*)d_in[5];
    const float* W1 = (const float*)d_in[6];
    const float* W2 = (const float*)d_in[7];
    const float* W3 = (const float*)d_in[8];
    float* outp = (float*)d_out;

    if (ws_size >= WS_NEED) {
        char* w = (char*)d_ws;
        int*      slots = (int*)(w + WS_SLOTS_OFF);
        int*      cnt   = (int*)(w + WS_CNT_OFF);
        _Float16* wbuf  = (_Float16*)(w + WS_WBUF_OFF);

        hipLaunchKernelGGL(prep_weights, dim3(36), dim3(64), 0, stream,
                           W0, W1, W2, W3, wbuf, cnt);
        hipLaunchKernelGGL(csr_build, dim3((NE + 255) / 256), dim3(256), 0, stream,
                           receivers, cnt, slots);
        hipLaunchKernelGGL(fused_mp_kernel, dim3(NN / 4), dim3(256), 0, stream,
                           node_feats, edge_attrs, edge_feats, senders,
                           wbuf, cnt, slots, outp);
    } else {
        hipMemsetAsync(d_out, 0, (size_t)out_size * sizeof(float), stream);
        hipLaunchKernelGGL(edge_mp_kernel, dim3((NE + 127) / 128), dim3(128), 0, stream,
                           node_feats, edge_attrs, edge_feats, senders, receivers,
                           W0, W1, W2, W3, outp);
    }
}